// Round 1
// baseline (36670.868 us; speedup 1.0000x reference)
//
#include <hip/hip_runtime.h>
#include <hip/hip_fp16.h>

// Problem: unbatched GRU scanned over batch-flattened sequence.
//   Encoder: 30720 serial steps, Decoder: 3840 serial steps (independent chains).
//   Per step: gh = W_hh (768x256) . h (256)  -- serial in h.
// Strategy:
//   K1: precompute gi = x @ W_ih^T + b_ih for all rows (parallel GEMM) -> ws as f16.
//   K2: 2 blocks (enc, dec), 768 threads each; W_hh row-resident in VGPRs as half2;
//       h broadcast via LDS; v_dot2_f32_f16 inner product; 2 barriers/step.

typedef _Float16 h2 __attribute__((ext_vector_type(2)));
typedef _Float16 h4 __attribute__((ext_vector_type(4)));

union HU { unsigned int u; h2 v; };

__device__ __forceinline__ float fdot2(h2 a, h2 b, float c) {
#if __has_builtin(__builtin_amdgcn_fdot2)
  return __builtin_amdgcn_fdot2(a, b, c, false);
#else
  return c + (float)a[0] * (float)b[0] + (float)a[1] * (float)b[1];
#endif
}

__device__ __forceinline__ float fast_sigmoid(float x) {
  // 1/(1+2^(-x*log2 e)); rcp+exp2 are ~1ulp -> plenty for 1.8e-2 tolerance
  return __builtin_amdgcn_rcpf(1.0f + __builtin_amdgcn_exp2f(x * -1.4426950408889634f));
}

constexpr int B = 128, T_IN = 240, T_OUT = 30, D = 128, H = 256, G = 768; // G = 3H
constexpr int L_ENC = B * T_IN;   // 30720
constexpr int L_DEC = B * T_OUT;  // 3840
// workspace need: (L_ENC + L_DEC) * G * sizeof(_Float16) = 53,084,160 bytes

// ---------------- K1: gi = x @ W_ih^T + b_ih (both enc and dec segments) ----
// grid: (12 col-tiles of 64, 540 row-blocks of 64), block 256.
__global__ __launch_bounds__(256) void gi_gemm(
    const float* __restrict__ x,
    const float* __restrict__ Wih_e, const float* __restrict__ bih_e,
    const float* __restrict__ Wih_d, const float* __restrict__ bih_d,
    _Float16* __restrict__ gi)
{
  const int jt = blockIdx.x;            // 0..11
  const int by = blockIdx.y;            // 0..539
  const bool enc = by < (L_ENC / 64);
  const int row0 = enc ? by * 64 : (by - L_ENC / 64) * 64;  // segment-local
  const float* __restrict__ W  = enc ? Wih_e : Wih_d;
  const float* __restrict__ bi = enc ? bih_e : bih_d;
  _Float16* __restrict__ gout = enc ? gi : gi + (size_t)L_ENC * G;

  __shared__ float xs[64][132];   // +4 pad: row stride 132 dwords
  __shared__ float ws[64][132];
  const int t = threadIdx.x;
#pragma unroll
  for (int p = 0; p < 8; ++p) {
    int idx = p * 256 + t;        // 2048 float4 total
    int r  = idx >> 5;            // row 0..63
    int c4 = (idx & 31) * 4;      // col 0..124
    int i  = row0 + r;
    int bb = i & (B - 1);
    int tt = i >> 7;
    if (!enc) tt *= 8;            // decoder reads x[:, ::8, :]
    float4 xv = *(const float4*)(x + (size_t)(bb * T_IN + tt) * D + c4);
    *(float4*)&xs[r][c4] = xv;
    float4 wv = *(const float4*)(W + (size_t)(jt * 64 + r) * D + c4);
    *(float4*)&ws[r][c4] = wv;
  }
  __syncthreads();

  const int tr = t >> 4, tc = t & 15;   // 16x16 threads -> 4x4 outputs each
  float acc[4][4] = {};
  for (int k4 = 0; k4 < 128; k4 += 4) {
    float4 xa[4], wa[4];
#pragma unroll
    for (int q = 0; q < 4; ++q) xa[q] = *(const float4*)&xs[tr * 4 + q][k4];
#pragma unroll
    for (int q = 0; q < 4; ++q) wa[q] = *(const float4*)&ws[tc * 4 + q][k4];
#pragma unroll
    for (int r = 0; r < 4; ++r)
#pragma unroll
      for (int c = 0; c < 4; ++c)
        acc[r][c] += xa[r].x * wa[c].x + xa[r].y * wa[c].y +
                     xa[r].z * wa[c].z + xa[r].w * wa[c].w;
  }

  const int col = jt * 64 + tc * 4;
  float bv[4];
#pragma unroll
  for (int c = 0; c < 4; ++c) bv[c] = bi[col + c];
#pragma unroll
  for (int r = 0; r < 4; ++r) {
    int grow = row0 + tr * 4 + r;
    h4 o;
#pragma unroll
    for (int c = 0; c < 4; ++c) o[c] = (_Float16)(acc[r][c] + bv[c]);
    *(h4*)(gout + (size_t)grow * G + col) = o;   // 8B store, 8B-aligned
  }
}

// ---------------- K2: serial GRU scan --------------------------------------
// block 0 = encoder (30720 steps), block 1 = decoder (3840 steps).
// 768 threads = 12 waves on one CU; thread tid owns W_hh row tid (128 half2 VGPRs).
__global__ __launch_bounds__(768) void gru_serial(
    const _Float16* __restrict__ gi,
    const float* __restrict__ Whh_e, const float* __restrict__ bhh_e,
    const float* __restrict__ Whh_d, const float* __restrict__ bhh_d,
    float* __restrict__ out)
{
  const int tid = threadIdx.x;
  const bool enc = (blockIdx.x == 0);
  const int L = enc ? L_ENC : L_DEC;
  const float* __restrict__ W  = enc ? Whh_e : Whh_d;
  const float* __restrict__ bh = enc ? bhh_e : bhh_d;
  const _Float16* __restrict__ gbase = enc ? gi : gi + (size_t)L_ENC * G;
  float* __restrict__ obase = enc ? out : out + T_IN * H;

  __shared__ __align__(16) unsigned int h_lds[H / 2]; // 256 f16 as 128 uints
  __shared__ float gh_lds[G];                          // pre-activations (h-part, +gi for r/z)
  __shared__ float gin_lds[H];                         // gi_n kept separate (r multiplies only h_n)

  // Load W_hh row tid -> 128 half2 registers (one-time, ~1KB/thread).
  h2 w[128];
  {
    const float4* wr = (const float4*)(W + (size_t)tid * H);
#pragma unroll
    for (int c = 0; c < 64; ++c) {
      float4 f = wr[c];
      h2 a; a[0] = (_Float16)f.x; a[1] = (_Float16)f.y;
      h2 b; b[0] = (_Float16)f.z; b[1] = (_Float16)f.w;
      w[2 * c]     = a;
      w[2 * c + 1] = b;
    }
  }
  const float bhh_r = bh[tid];
  if (tid < H / 2) h_lds[tid] = 0u;   // h0 = 0
  float h_old = 0.0f;                 // f32 copy of h[tid] for tid < H
  __syncthreads();

  float gnext = (float)gbase[tid];    // prefetch gi[0][tid]
  for (int i = 0; i < L; ++i) {
    const float gcur = gnext;
    {
      int inext = (i + 1 < L) ? (i + 1) : i;
      gnext = (float)gbase[(size_t)inext * G + tid];  // latency hidden by matvec
    }
    // gh[tid] = dot(W_hh[tid,:], h) ; 4 independent accumulator chains for ILP
    float a0 = 0.f, a1 = 0.f, a2 = 0.f, a3 = 0.f;
    const uint4* hp = (const uint4*)h_lds;
#pragma unroll
    for (int c = 0; c < 32; ++c) {
      uint4 hv = hp[c];               // ds_read_b128, broadcast (all lanes same addr)
      HU u0, u1, u2, u3;
      u0.u = hv.x; u1.u = hv.y; u2.u = hv.z; u3.u = hv.w;
      a0 = fdot2(w[4 * c + 0], u0.v, a0);
      a1 = fdot2(w[4 * c + 1], u1.v, a1);
      a2 = fdot2(w[4 * c + 2], u2.v, a2);
      a3 = fdot2(w[4 * c + 3], u3.v, a3);
    }
    const float acc = ((a0 + a1) + (a2 + a3)) + bhh_r;
    if (tid < 2 * H) {
      gh_lds[tid] = acc + gcur;       // r,z rows: fold gi in
    } else {
      gh_lds[tid] = acc;              // n row: keep h-part separate
      gin_lds[tid - 2 * H] = gcur;
    }
    __syncthreads();                  // gh visible; everyone past h_lds reads

    if (tid < H) {
      const float pr = gh_lds[tid];
      const float pz = gh_lds[H + tid];
      const float hn = gh_lds[2 * H + tid];
      const float gn = gin_lds[tid];
      const float r = fast_sigmoid(pr);
      const float z = fast_sigmoid(pz);
      const float n = 2.0f * fast_sigmoid(2.0f * (gn + r * hn)) - 1.0f; // tanh
      const float hnew = (1.0f - z) * n + z * h_old;
      h_old = hnew;
      ((_Float16*)h_lds)[tid] = (_Float16)hnew;
      if (enc) {
        if ((i & (B - 1)) == (B - 1))             // every 128th step
          obase[(i >> 7) * H + tid] = hnew;
      } else {
        // interped[b][t][:] = hs_d[t*128+b]
        obase[((i & (B - 1)) * T_OUT + (i >> 7)) * H + tid] = hnew;
      }
    }
    __syncthreads();                  // new h visible for next matvec
  }
}

extern "C" void kernel_launch(void* const* d_in, const int* in_sizes, int n_in,
                              void* d_out, int out_size, void* d_ws, size_t ws_size,
                              hipStream_t stream) {
  (void)in_sizes; (void)n_in; (void)out_size; (void)ws_size;
  const float* x     = (const float*)d_in[0];
  const float* Wih_e = (const float*)d_in[1];
  const float* Whh_e = (const float*)d_in[2];
  const float* bih_e = (const float*)d_in[3];
  const float* bhh_e = (const float*)d_in[4];
  const float* Wih_d = (const float*)d_in[5];
  const float* Whh_d = (const float*)d_in[6];
  const float* bih_d = (const float*)d_in[7];
  const float* bhh_d = (const float*)d_in[8];
  float* out = (float*)d_out;
  _Float16* gi = (_Float16*)d_ws;    // needs 53,084,160 B

  dim3 g1(12, (L_ENC + L_DEC) / 64);
  gi_gemm<<<g1, 256, 0, stream>>>(x, Wih_e, bih_e, Wih_d, bih_d, gi);
  gru_serial<<<dim3(2), dim3(768), 0, stream>>>(gi, Whh_e, bhh_e, Whh_d, bhh_d, out);
}